// Round 1
// 105.752 us; speedup vs baseline: 1.0689x; 1.0689x over previous
//
#include <hip/hip_runtime.h>
#include <hip/hip_bf16.h>
#include <math.h>

typedef __bf16 bf16;
typedef __bf16 bf16x8 __attribute__((ext_vector_type(8)));
typedef float  f32x4  __attribute__((ext_vector_type(4)));

#define NTOK   16384
#define DIN    512
#define DOUT   512
#define NTYPES 128
#define TEBD   128
#define NEXP   8
#define CAP    16384

// ---- workspace layout (bytes); total ~23.1 MB ----
#define WS_ROUTE_E 0                         // int[256]
#define WS_ROUTE_W 1024                      // float[256]
#define WS_CNT     2048                      // int[16]  (k*8+e)
#define WS_TOK     4096                      // int[16*CAP]   = 1 MB
#define WS_WGT     (WS_TOK + 16 * CAP * 4)   // float[16*CAP] = 1 MB
#define WS_XB      (WS_WGT + 16 * CAP * 4)   // bf16[16384*512]
#define WS_WET     (WS_XB + NTOK * DIN * 2)  // bf16[8*512*512]

#define GLOAD_LDS16(g, l)                                                     \
  __builtin_amdgcn_global_load_lds(                                           \
      (const __attribute__((address_space(1))) void*)(g),                     \
      (__attribute__((address_space(3))) void*)(l), 16, 0, 0)

// ---------------- routing: per-type logits -> top-2 -> softmax -------------
__global__ void route_kernel(const float* __restrict__ emb,
                             const float* __restrict__ Wg,
                             int* __restrict__ route_e,
                             float* __restrict__ route_w,
                             int* __restrict__ cnt) {
  int t = threadIdx.x;  // 128 threads = 128 types
  if (t < 16) cnt[t] = 0;
  if (t >= NTYPES) return;
  const float* er = emb + (size_t)t * TEBD;
  float lg[NEXP];
#pragma unroll
  for (int e = 0; e < NEXP; ++e) lg[e] = 0.f;
  for (int j = 0; j < TEBD; ++j) {
    float ev = er[j];
#pragma unroll
    for (int e = 0; e < NEXP; ++e) lg[e] += ev * Wg[j * NEXP + e];
  }
  float v0 = -__builtin_inff(), v1 = -__builtin_inff();
  int i0 = 0, i1 = 0;
#pragma unroll
  for (int e = 0; e < NEXP; ++e) {
    float v = lg[e];
    if (v > v0) { v1 = v0; i1 = i0; v0 = v; i0 = e; }
    else if (v > v1) { v1 = v; i1 = e; }
  }
  float d = expf(v1 - v0);
  float inv = 1.f / (1.f + d);
  route_e[t * 2 + 0] = i0;
  route_e[t * 2 + 1] = i1;
  route_w[t * 2 + 0] = inv;
  route_w[t * 2 + 1] = d * inv;
}

// ------------- bucket tokens into per-(k,expert) lists ---------------------
__global__ void fill_kernel(const int* __restrict__ atype,
                            const int* __restrict__ route_e,
                            const float* __restrict__ route_w,
                            int* __restrict__ cnt,
                            int* __restrict__ slot_token,
                            float* __restrict__ slot_w) {
  __shared__ int lc[16];
  __shared__ int lb[16];
  int tid = threadIdx.x;
  if (tid < 16) lc[tid] = 0;
  __syncthreads();
  int t = blockIdx.x * 256 + tid;
  int ty = atype[t];
  int e0 = route_e[ty * 2 + 0], e1 = route_e[ty * 2 + 1];
  int p0 = atomicAdd(&lc[e0], 1);        // list (k=0, e0)
  int p1 = atomicAdd(&lc[8 + e1], 1);    // list (k=1, e1)
  __syncthreads();
  if (tid < 16) lb[tid] = atomicAdd(&cnt[tid], lc[tid]);
  __syncthreads();
  int s0 = e0 * CAP + lb[e0] + p0;
  int s1 = (8 + e1) * CAP + lb[8 + e1] + p1;
  slot_token[s0] = t;  slot_w[s0] = route_w[ty * 2 + 0];
  slot_token[s1] = t;  slot_w[s1] = route_w[ty * 2 + 1];
}

// ---------------- x: f32 -> bf16 -------------------------------------------
__global__ void cvt_x_kernel(const float* __restrict__ x, bf16* __restrict__ xb) {
  int i = blockIdx.x * 256 + threadIdx.x;  // each handles 8 elems
  const float4* p = (const float4*)(x + (size_t)i * 8);
  float4 a = p[0], b = p[1];
  bf16x8 o;
  o[0] = (bf16)a.x; o[1] = (bf16)a.y; o[2] = (bf16)a.z; o[3] = (bf16)a.w;
  o[4] = (bf16)b.x; o[5] = (bf16)b.y; o[6] = (bf16)b.z; o[7] = (bf16)b.w;
  *(bf16x8*)(xb + (size_t)i * 8) = o;
}

// ---------------- We[e][k][n] f32 -> WeT[e][n][k] bf16 ---------------------
__global__ void cvt_weT_kernel(const float* __restrict__ We, bf16* __restrict__ WeT) {
  __shared__ float t[64][65];
  int bx = blockIdx.x;      // 512 = 8 experts * 8 * 8 tiles of 64x64
  int e = bx >> 6;
  int rem = bx & 63;
  int kt = (rem >> 3) * 64;
  int nt = (rem & 7) * 64;
  int tid = threadIdx.x;
  int col = tid & 63;
  int rq = tid >> 6;
#pragma unroll
  for (int r = 0; r < 16; ++r) {
    int row = rq * 16 + r;
    t[row][col] = We[((size_t)e * DIN + kt + row) * DOUT + nt + col];
  }
  __syncthreads();
#pragma unroll
  for (int r = 0; r < 16; ++r) {
    int n = rq * 16 + r;
    WeT[((size_t)e * DOUT + nt + n) * DIN + kt + col] = (bf16)t[col][n];
  }
}

// --------- grouped GEMM: two passes, 3-buf LDS, counted vmcnt --------------
// tile: BM=128 x BN=128, BK=32, 4 waves (2x2), 16x16x32 MFMA.
// Pipeline: stage 2 tiles ahead; per iter wait vmcnt(4) (tile t landed,
// tiles t+1/t+2 still in flight), raw s_barrier, stage t+2, compute t.
//
// KOFF=0 (k=0 lists): every token appears in EXACTLY ONE k=0 list, so the
//   epilogue is a plain store (no memset, no atomics).
// KOFF=8 (k=1 lists): launched after pass A on the same stream; each token
//   appears in exactly one k=1 list -> unique writer -> plain load+add+store.
// This removes all 16.7M global f32 atomicAdds (the round-0 bottleneck: L2
// processes dword atomics per-element; we measured 194G atomic/s sustained
// with MFMA/VALU/HBM all idle) and the 33MB memset.
template <int KOFF>
__global__ __launch_bounds__(256, 3) void moe_gemm_kernel(
    const bf16* __restrict__ xb, const bf16* __restrict__ WeT,
    const float* __restrict__ be, const int* __restrict__ cnt,
    const int* __restrict__ slot_token, const float* __restrict__ slot_w,
    float* __restrict__ out) {
  int list = KOFF + blockIdx.z;    // 8 lists per pass
  int e = list & 7;
  int ne = cnt[list];
  int r0 = blockIdx.y * 128;
  if (r0 >= ne) return;
  int c0 = blockIdx.x * 128;

  __shared__ __align__(16) bf16 As[3][128 * 32];
  __shared__ __align__(16) bf16 Bs[3][128 * 32];
  __shared__ int   tokS[128];
  __shared__ float wS[128];
  __shared__ float beS[128];

  int tid = threadIdx.x;
  int lane = tid & 63, w = tid >> 6;

  if (tid < 128) {
    int g = r0 + tid;
    int s = (g < ne) ? g : (ne - 1);  // clamp tail rows to a valid slot
    tokS[tid] = slot_token[list * CAP + s];
    wS[tid]   = slot_w[list * CAP + s];
    beS[tid]  = be[e * DOUT + c0 + tid];
  }
  __syncthreads();  // full drain: vmcnt clean slate before pipeline

  // per-lane global sources; chunk swizzle c = cs ^ ((row>>1)&3) keeps the
  // ds_read_b128 side bank-balanced while gload_lds dest stays linear
  const bf16* srcA[2];
  const bf16* srcB[2];
#pragma unroll
  for (int j = 0; j < 2; ++j) {
    int slot = w * 128 + j * 64 + lane;
    int row = slot >> 2, cs = slot & 3;
    int c = cs ^ ((row >> 1) & 3);
    srcA[j] = xb + (size_t)tokS[row] * DIN + c * 8;
    srcB[j] = WeT + ((size_t)e * DOUT + c0 + row) * DIN + c * 8;
  }

  f32x4 acc[4][4];
#pragma unroll
  for (int mi = 0; mi < 4; ++mi)
#pragma unroll
    for (int ni = 0; ni < 4; ++ni) acc[mi][ni] = (f32x4)0.f;

  int wm = (w >> 1) * 64;
  int wn = (w & 1) * 64;
  int r16 = lane & 15, g16 = lane >> 4;

  int offA[4], offB[4];
#pragma unroll
  for (int i = 0; i < 4; ++i) {
    int rA = wm + i * 16 + r16;
    offA[i] = rA * 32 + (g16 ^ ((rA >> 1) & 3)) * 8;
    int rB = wn + i * 16 + r16;
    offB[i] = rB * 32 + (g16 ^ ((rB >> 1) & 3)) * 8;
  }

  auto stage = [&](int buf) {  // 4 gload_lds per wave, then advance one BK
#pragma unroll
    for (int j = 0; j < 2; ++j) {
      GLOAD_LDS16(srcA[j], &As[buf][(w * 128 + j * 64) * 8]);
      GLOAD_LDS16(srcB[j], &Bs[buf][(w * 128 + j * 64) * 8]);
      srcA[j] += 32;
      srcB[j] += 32;
    }
  };

  // prologue: tiles 0 and 1 in flight (8 loads/wave)
  stage(0);
  stage(1);

#pragma unroll
  for (int t = 0; t < 16; ++t) {
    // wait for tile t only: leaves the newer prefetches in flight
    if (t < 15) asm volatile("s_waitcnt vmcnt(4)" ::: "memory");
    else        asm volatile("s_waitcnt vmcnt(0)" ::: "memory");
    __builtin_amdgcn_s_barrier();
    // safe to overwrite buf[(t+2)%3] == buf[(t-1)%3]: all waves passed the
    // barrier, hence finished their iter t-1 ds_reads (MFMA consumed them)
    if (t + 2 < 16) stage((t + 2) % 3);

    int cur = t % 3;
    bf16x8 af[4], bfr[4];
#pragma unroll
    for (int i = 0; i < 4; ++i) af[i] = *(const bf16x8*)&As[cur][offA[i]];
#pragma unroll
    for (int i = 0; i < 4; ++i) bfr[i] = *(const bf16x8*)&Bs[cur][offB[i]];
    __builtin_amdgcn_s_setprio(1);
#pragma unroll
    for (int mi = 0; mi < 4; ++mi)
#pragma unroll
      for (int ni = 0; ni < 4; ++ni)
        acc[mi][ni] = __builtin_amdgcn_mfma_f32_16x16x32_bf16(
            af[mi], bfr[ni], acc[mi][ni], 0, 0, 0);
    __builtin_amdgcn_s_setprio(0);
  }

  // ---- epilogue: +bias, tanh, *weight; store (pass A) or RMW (pass B) -----
#pragma unroll
  for (int mi = 0; mi < 4; ++mi) {
#pragma unroll
    for (int ni = 0; ni < 4; ++ni) {
      f32x4 v = acc[mi][ni];
      int colLocal = wn + ni * 16 + r16;
      float bev = beS[colLocal];
#pragma unroll
      for (int r = 0; r < 4; ++r) {
        int lrow = wm + mi * 16 + g16 * 4 + r;
        if (r0 + lrow < ne) {
          float val = tanhf(v[r] + bev) * wS[lrow];
          float* p = out + (size_t)tokS[lrow] * DOUT + c0 + colLocal;
          if constexpr (KOFF == 0) {
            *p = val;            // unique writer across pass A
          } else {
            *p = *p + val;       // unique writer within pass B; pass A done
          }
        }
      }
    }
  }
}

extern "C" void kernel_launch(void* const* d_in, const int* in_sizes, int n_in,
                              void* d_out, int out_size, void* d_ws, size_t ws_size,
                              hipStream_t stream) {
  const float* x    = (const float*)d_in[0];
  const float* emb  = (const float*)d_in[1];
  const int*   aty  = (const int*)d_in[2];
  const float* Wg   = (const float*)d_in[3];
  const float* We   = (const float*)d_in[4];
  const float* be   = (const float*)d_in[5];
  float* out = (float*)d_out;

  char* ws = (char*)d_ws;
  int*   route_e    = (int*)(ws + WS_ROUTE_E);
  float* route_w    = (float*)(ws + WS_ROUTE_W);
  int*   cnt        = (int*)(ws + WS_CNT);
  int*   slot_token = (int*)(ws + WS_TOK);
  float* slot_w     = (float*)(ws + WS_WGT);
  bf16*  xb         = (bf16*)(ws + WS_XB);
  bf16*  WeT        = (bf16*)(ws + WS_WET);

  route_kernel<<<1, 128, 0, stream>>>(emb, Wg, route_e, route_w, cnt);
  fill_kernel<<<NTOK / 256, 256, 0, stream>>>(aty, route_e, route_w, cnt,
                                              slot_token, slot_w);
  cvt_x_kernel<<<(NTOK * DIN / 8) / 256, 256, 0, stream>>>(x, xb);
  cvt_weT_kernel<<<512, 256, 0, stream>>>(We, WeT);
  // pass A: k=0 lists, plain stores (every token exactly once -> no memset)
  moe_gemm_kernel<0><<<dim3(4, 128, 8), 256, 0, stream>>>(
      xb, WeT, be, cnt, slot_token, slot_w, out);
  // pass B: k=1 lists, plain load+add+store (unique writer per element)
  moe_gemm_kernel<8><<<dim3(4, 128, 8), 256, 0, stream>>>(
      xb, WeT, be, cnt, slot_token, slot_w, out);
}

// Round 2
// 78.993 us; speedup vs baseline: 1.4310x; 1.3387x over previous
//
#include <hip/hip_runtime.h>
#include <hip/hip_bf16.h>
#include <math.h>

typedef __bf16 bf16;
typedef __bf16 bf16x8 __attribute__((ext_vector_type(8)));
typedef float  f32x4  __attribute__((ext_vector_type(4)));

#define NTOK   16384
#define DIN    512
#define DOUT   512
#define NTYPES 128
#define TEBD   128
#define NEXP   8
#define NPAIR  64      // pair key = e0*8+e1 (e0 = top-1, e1 = top-2, always distinct)
#define MAXTILE 192    // sum_l ceil(n_l/128) <= 64 + 16384/128 = 192

// ---- workspace layout (bytes); total ~21.2 MB ----
#define WS_ROUTE_P 0                          // int[128]    pair per type
#define WS_ROUTE_W 1024                       // float2[128] (w0,w1) per type
#define WS_CNT     3072                       // int[64]
#define WS_OFF     3584                       // int[64]
#define WS_BASE    4096                       // int[64]
#define WS_NTILE   4608                       // int[1]
#define WS_TMAP    5120                       // int2[192] (list, r0)
#define WS_RMAP    8192                       // int[16384] packed row -> token
#define WS_WGT     (WS_RMAP + NTOK * 4)       // float2[16384] packed row -> (w0,w1)
#define WS_XG      (WS_WGT + NTOK * 8)        // bf16[16384*512] pair-sorted x (16 MB)
#define WS_WET     (WS_XG + (size_t)NTOK * DIN * 2)  // bf16[8*512*512] (4 MB)

#define GLOAD_LDS16(g, l)                                                     \
  __builtin_amdgcn_global_load_lds(                                           \
      (const __attribute__((address_space(1))) void*)(g),                     \
      (__attribute__((address_space(3))) void*)(l), 16, 0, 0)

// ---------------- routing: per-type logits -> top-2 -> softmax -------------
__global__ void route_kernel(const float* __restrict__ emb,
                             const float* __restrict__ Wg,
                             int* __restrict__ route_p,
                             float* __restrict__ route_w,   // float2 per type
                             int* __restrict__ cnt,
                             int* __restrict__ off) {
  int t = threadIdx.x;  // 128 threads = 128 types
  if (t < NPAIR) { cnt[t] = 0; off[t] = 0; }
  if (t >= NTYPES) return;
  const float* er = emb + (size_t)t * TEBD;
  float lg[NEXP];
#pragma unroll
  for (int e = 0; e < NEXP; ++e) lg[e] = 0.f;
  for (int j = 0; j < TEBD; ++j) {
    float ev = er[j];
#pragma unroll
    for (int e = 0; e < NEXP; ++e) lg[e] += ev * Wg[j * NEXP + e];
  }
  float v0 = -__builtin_inff(), v1 = -__builtin_inff();
  int i0 = 0, i1 = 0;
#pragma unroll
  for (int e = 0; e < NEXP; ++e) {
    float v = lg[e];
    if (v > v0) { v1 = v0; i1 = i0; v0 = v; i0 = e; }
    else if (v > v1) { v1 = v; i1 = e; }
  }
  float d = expf(v1 - v0);
  float inv = 1.f / (1.f + d);
  route_p[t] = i0 * 8 + i1;
  route_w[t * 2 + 0] = inv;
  route_w[t * 2 + 1] = d * inv;
}

// ------------- histogram tokens into 64 pair buckets -----------------------
__global__ void count_kernel(const int* __restrict__ atype,
                             const int* __restrict__ route_p,
                             int* __restrict__ cnt) {
  __shared__ int lc[NPAIR];
  int tid = threadIdx.x;
  if (tid < NPAIR) lc[tid] = 0;
  __syncthreads();
  int t = blockIdx.x * 256 + tid;
  int p = route_p[atype[t]];
  atomicAdd(&lc[p], 1);
  __syncthreads();
  if (tid < NPAIR && lc[tid]) atomicAdd(&cnt[tid], lc[tid]);
}

// ------------- exclusive scan of cnt + build tile table --------------------
__global__ void scan_kernel(const int* __restrict__ cnt,
                            int* __restrict__ base,
                            int* __restrict__ ntile,
                            int* __restrict__ tmap) {
  __shared__ int sb[NPAIR];
  __shared__ int st[NPAIR];
  int l = threadIdx.x;  // 64 threads
  int c = cnt[l];
  sb[l] = c;
  st[l] = (c + 127) >> 7;
  __syncthreads();
  int b = 0, tb = 0;
  for (int j = 0; j < l; ++j) { b += sb[j]; tb += st[j]; }
  base[l] = b;
  int nt_l = st[l];
  for (int i = 0; i < nt_l; ++i) {
    tmap[(tb + i) * 2 + 0] = l;
    tmap[(tb + i) * 2 + 1] = i * 128;
  }
  if (l == NPAIR - 1) ntile[0] = tb + nt_l;
}

// ------------- assign packed row index to each token -----------------------
__global__ void place_kernel(const int* __restrict__ atype,
                             const int* __restrict__ route_p,
                             const float* __restrict__ route_w,
                             const int* __restrict__ base,
                             int* __restrict__ off,
                             int* __restrict__ row_map,
                             float* __restrict__ wgt) {  // float2 per packed row
  __shared__ int lc[NPAIR];
  __shared__ int lb[NPAIR];
  int tid = threadIdx.x;
  if (tid < NPAIR) lc[tid] = 0;
  __syncthreads();
  int t = blockIdx.x * 256 + tid;
  int ty = atype[t];
  int p = route_p[ty];
  int r = atomicAdd(&lc[p], 1);
  __syncthreads();
  if (tid < NPAIR) lb[tid] = lc[tid] ? atomicAdd(&off[tid], lc[tid]) : 0;
  __syncthreads();
  int pos = base[p] + lb[p] + r;
  row_map[pos] = t;
  ((float2*)wgt)[pos] = ((const float2*)route_w)[ty];
}

// ------------- gather + f32->bf16 convert into pair-sorted xg --------------
__global__ void gather_cvt_kernel(const float* __restrict__ x,
                                  const int* __restrict__ row_map,
                                  bf16* __restrict__ xg) {
  int gid = blockIdx.x * 256 + threadIdx.x;  // 64 threads per row, 8 f32 each
  int row = gid >> 6;
  int c8 = (gid & 63) * 8;
  int tok = row_map[row];
  const float4* p = (const float4*)(x + (size_t)tok * DIN + c8);
  float4 a = p[0], b = p[1];
  bf16x8 o;
  o[0] = (bf16)a.x; o[1] = (bf16)a.y; o[2] = (bf16)a.z; o[3] = (bf16)a.w;
  o[4] = (bf16)b.x; o[5] = (bf16)b.y; o[6] = (bf16)b.z; o[7] = (bf16)b.w;
  *(bf16x8*)(xg + (size_t)row * DIN + c8) = o;
}

// ---------------- We[e][k][n] f32 -> WeT[e][n][k] bf16 ---------------------
__global__ void cvt_weT_kernel(const float* __restrict__ We, bf16* __restrict__ WeT) {
  __shared__ float t[64][65];
  int bx = blockIdx.x;      // 512 = 8 experts * 8 * 8 tiles of 64x64
  int e = bx >> 6;
  int rem = bx & 63;
  int kt = (rem >> 3) * 64;
  int nt = (rem & 7) * 64;
  int tid = threadIdx.x;
  int col = tid & 63;
  int rq = tid >> 6;
#pragma unroll
  for (int r = 0; r < 16; ++r) {
    int row = rq * 16 + r;
    t[row][col] = We[((size_t)e * DIN + kt + row) * DOUT + nt + col];
  }
  __syncthreads();
#pragma unroll
  for (int r = 0; r < 16; ++r) {
    int n = rq * 16 + r;
    WeT[((size_t)e * DOUT + nt + n) * DIN + kt + col] = (bf16)t[col][n];
  }
}

// --------- pair-merged grouped GEMM: one dispatch, both experts ------------
// tile: BM=128 x BN=64, BK=32, 4 waves (2x2 over 128x64), 16x16x32 MFMA.
// Per iter: stage A(8KB, contiguous rows of xg) + B0(4KB) + B1(4KB);
// compute 8 MFMA vs We[e0] and 8 vs We[e1] sharing the A fragments.
// 3-buf LDS (~50 KB -> 3 blocks/CU), counted vmcnt(4) keeps tile t+1 in
// flight. Epilogue: out = w0*tanh(acc0+b0) + w1*tanh(acc1+b1), one plain
// scattered store per element (each token in exactly one pair list -> no
// memset, no atomics, no RMW).
__global__ __launch_bounds__(256, 3) void moe_gemm_pair_kernel(
    const bf16* __restrict__ xg, const bf16* __restrict__ WeT,
    const float* __restrict__ be, const int* __restrict__ cnt,
    const int* __restrict__ base, const int* __restrict__ ntile,
    const int* __restrict__ tmap, const int* __restrict__ row_map,
    const float* __restrict__ wgt, float* __restrict__ out) {
  int nwork = ntile[0] * 8;
  int f = blockIdx.y * 8 + blockIdx.x;
  if (f >= nwork) return;
  // bijective chunked XCD swizzle over the working range: logical tile L
  // (row-tile-major, 8 col blocks adjacent) -> contiguous chunk per XCD,
  // so same-list A rows and B panels stay L2-local.
  int q = nwork >> 3, r = nwork & 7;
  int xcd = f & 7, idx = f >> 3;
  int L = (xcd < r ? xcd * (q + 1) : r * (q + 1) + (xcd - r) * q) + idx;
  int ti = L >> 3;
  int cx = L & 7;
  int list = tmap[ti * 2 + 0];
  int r0   = tmap[ti * 2 + 1];
  int e0 = list >> 3, e1 = list & 7;
  int nrow = cnt[list] - r0;
  if (nrow > 128) nrow = 128;
  int c0 = cx * 64;
  int arow0 = base[list] + r0;

  __shared__ __align__(16) bf16 As[3][128 * 32];
  __shared__ __align__(16) bf16 B0s[3][64 * 32];
  __shared__ __align__(16) bf16 B1s[3][64 * 32];
  __shared__ int   tokS[128];
  __shared__ float w0S[128], w1S[128];
  __shared__ float be0S[64], be1S[64];

  int tid = threadIdx.x;
  int lane = tid & 63, w = tid >> 6;

  if (tid < 128) {
    int srow = (tid < nrow) ? tid : (nrow - 1);
    int gl = arow0 + srow;
    tokS[tid] = row_map[gl];
    float2 ww = ((const float2*)wgt)[gl];
    w0S[tid] = ww.x;
    w1S[tid] = ww.y;
    if (tid < 64) {
      be0S[tid] = be[e0 * DOUT + c0 + tid];
      be1S[tid] = be[e1 * DOUT + c0 + tid];
    }
  }
  __syncthreads();  // full drain: clean vmcnt slate before pipeline

  // per-lane global sources; chunk swizzle c = cs ^ ((row>>1)&3) keeps the
  // ds_read_b128 side bank-balanced while gload_lds dest stays linear
  const bf16* srcA[2];
#pragma unroll
  for (int j = 0; j < 2; ++j) {
    int slot = w * 128 + j * 64 + lane;
    int row = slot >> 2, cs = slot & 3;
    int c = cs ^ ((row >> 1) & 3);
    int srow = (row < nrow) ? row : (nrow - 1);
    srcA[j] = xg + (size_t)(arow0 + srow) * DIN + c * 8;
  }
  const bf16* srcB0;
  const bf16* srcB1;
  {
    int slot = w * 64 + lane;
    int row = slot >> 2, cs = slot & 3;
    int c = cs ^ ((row >> 1) & 3);
    srcB0 = WeT + ((size_t)e0 * DOUT + c0 + row) * DIN + c * 8;
    srcB1 = WeT + ((size_t)e1 * DOUT + c0 + row) * DIN + c * 8;
  }

  f32x4 acc0[4][2], acc1[4][2];
#pragma unroll
  for (int mi = 0; mi < 4; ++mi)
#pragma unroll
    for (int ni = 0; ni < 2; ++ni) { acc0[mi][ni] = (f32x4)0.f; acc1[mi][ni] = (f32x4)0.f; }

  int wm = (w >> 1) * 64;
  int wn = (w & 1) * 32;
  int r16 = lane & 15, g16 = lane >> 4;

  int offA[4], offB[2];
#pragma unroll
  for (int i = 0; i < 4; ++i) {
    int rA = wm + i * 16 + r16;
    offA[i] = rA * 32 + (g16 ^ ((rA >> 1) & 3)) * 8;
  }
#pragma unroll
  for (int i = 0; i < 2; ++i) {
    int rB = wn + i * 16 + r16;
    offB[i] = rB * 32 + (g16 ^ ((rB >> 1) & 3)) * 8;
  }

  auto stage = [&](int buf) {  // 4 gload_lds per wave, then advance one BK
#pragma unroll
    for (int j = 0; j < 2; ++j) {
      GLOAD_LDS16(srcA[j], &As[buf][(w * 128 + j * 64) * 8]);
      srcA[j] += 32;
    }
    GLOAD_LDS16(srcB0, &B0s[buf][w * 64 * 8]);
    GLOAD_LDS16(srcB1, &B1s[buf][w * 64 * 8]);
    srcB0 += 32;
    srcB1 += 32;
  };

  // prologue: tiles 0 and 1 in flight (8 loads/wave)
  stage(0);
  stage(1);

#pragma unroll
  for (int t = 0; t < 16; ++t) {
    // wait for tile t only: leaves the newer prefetch in flight
    if (t < 15) asm volatile("s_waitcnt vmcnt(4)" ::: "memory");
    else        asm volatile("s_waitcnt vmcnt(0)" ::: "memory");
    __builtin_amdgcn_s_barrier();
    // safe to overwrite buf[(t+2)%3] == buf[(t-1)%3]: all waves passed the
    // barrier, hence finished their iter t-1 ds_reads (MFMA consumed them)
    if (t + 2 < 16) stage((t + 2) % 3);

    int cur = t % 3;
    bf16x8 af[4], b0f[2], b1f[2];
#pragma unroll
    for (int i = 0; i < 4; ++i) af[i] = *(const bf16x8*)&As[cur][offA[i]];
#pragma unroll
    for (int i = 0; i < 2; ++i) b0f[i] = *(const bf16x8*)&B0s[cur][offB[i]];
#pragma unroll
    for (int i = 0; i < 2; ++i) b1f[i] = *(const bf16x8*)&B1s[cur][offB[i]];
    __builtin_amdgcn_s_setprio(1);
#pragma unroll
    for (int mi = 0; mi < 4; ++mi)
#pragma unroll
      for (int ni = 0; ni < 2; ++ni) {
        acc0[mi][ni] = __builtin_amdgcn_mfma_f32_16x16x32_bf16(
            af[mi], b0f[ni], acc0[mi][ni], 0, 0, 0);
        acc1[mi][ni] = __builtin_amdgcn_mfma_f32_16x16x32_bf16(
            af[mi], b1f[ni], acc1[mi][ni], 0, 0, 0);
      }
    __builtin_amdgcn_s_setprio(0);
  }

  // ---- epilogue: out = w0*tanh(acc0+b0) + w1*tanh(acc1+b1), plain store ---
#pragma unroll
  for (int mi = 0; mi < 4; ++mi) {
#pragma unroll
    for (int ni = 0; ni < 2; ++ni) {
      f32x4 v0 = acc0[mi][ni];
      f32x4 v1 = acc1[mi][ni];
      int colLocal = wn + ni * 16 + r16;
      float bev0 = be0S[colLocal];
      float bev1 = be1S[colLocal];
#pragma unroll
      for (int r = 0; r < 4; ++r) {
        int lrow = wm + mi * 16 + g16 * 4 + r;
        if (lrow < nrow) {
          float val = tanhf(v0[r] + bev0) * w0S[lrow] +
                      tanhf(v1[r] + bev1) * w1S[lrow];
          out[(size_t)tokS[lrow] * DOUT + c0 + colLocal] = val;
        }
      }
    }
  }
}

extern "C" void kernel_launch(void* const* d_in, const int* in_sizes, int n_in,
                              void* d_out, int out_size, void* d_ws, size_t ws_size,
                              hipStream_t stream) {
  const float* x    = (const float*)d_in[0];
  const float* emb  = (const float*)d_in[1];
  const int*   aty  = (const int*)d_in[2];
  const float* Wg   = (const float*)d_in[3];
  const float* We   = (const float*)d_in[4];
  const float* be   = (const float*)d_in[5];
  float* out = (float*)d_out;

  char* ws = (char*)d_ws;
  int*   route_p  = (int*)(ws + WS_ROUTE_P);
  float* route_w  = (float*)(ws + WS_ROUTE_W);
  int*   cnt      = (int*)(ws + WS_CNT);
  int*   off      = (int*)(ws + WS_OFF);
  int*   base     = (int*)(ws + WS_BASE);
  int*   ntile    = (int*)(ws + WS_NTILE);
  int*   tmap     = (int*)(ws + WS_TMAP);
  int*   row_map  = (int*)(ws + WS_RMAP);
  float* wgt      = (float*)(ws + WS_WGT);
  bf16*  xg       = (bf16*)(ws + WS_XG);
  bf16*  WeT      = (bf16*)(ws + WS_WET);

  route_kernel<<<1, 128, 0, stream>>>(emb, Wg, route_p, route_w, cnt, off);
  count_kernel<<<NTOK / 256, 256, 0, stream>>>(aty, route_p, cnt);
  scan_kernel<<<1, 64, 0, stream>>>(cnt, base, ntile, tmap);
  place_kernel<<<NTOK / 256, 256, 0, stream>>>(aty, route_p, route_w, base, off,
                                               row_map, wgt);
  gather_cvt_kernel<<<(NTOK * 64) / 256, 256, 0, stream>>>(x, row_map, xg);
  cvt_weT_kernel<<<512, 256, 0, stream>>>(We, WeT);
  // every out element written exactly once -> no memset needed
  moe_gemm_pair_kernel<<<dim3(8, MAXTILE), 256, 0, stream>>>(
      xg, WeT, be, cnt, base, ntile, tmap, row_map, wgt, out);
}

// Round 3
// 77.874 us; speedup vs baseline: 1.4516x; 1.0144x over previous
//
#include <hip/hip_runtime.h>
#include <hip/hip_bf16.h>
#include <math.h>

typedef __bf16 bf16;
typedef __bf16 bf16x8 __attribute__((ext_vector_type(8)));
typedef float  f32x4  __attribute__((ext_vector_type(4)));

#define NTOK   16384
#define DIN    512
#define DOUT   512
#define NTYPES 128
#define TEBD   128
#define NEXP   8
#define NPAIR  64      // pair key = e0*8+e1 (e0 = top-1, e1 = top-2, always distinct)
#define MAXTILE 192    // sum_l ceil(n_l/128) <= 64 + 16384/128 = 192

// ---- workspace layout (bytes); total ~21.2 MB ----
#define WS_HIST    0                          // int[128]   per-type token count
#define WS_ROUTE_W 512                        // float2[128] (w0,w1) per type
#define WS_BASET   1536                       // int[128]   packed base per type
#define WS_CURS    2048                       // int[128]   per-type cursor
#define WS_CNTP    2560                       // int[64]    per-pair count
#define WS_BASEP   2816                       // int[64]    per-pair base
#define WS_NTILE   3072                       // int[1]
#define WS_TMAP    3584                       // int2[192] (list, r0)
#define WS_RMAP    5120                       // int[16384] packed row -> token
#define WS_WGT     (WS_RMAP + NTOK * 4)       // float2[16384] packed row -> (w0,w1)
#define WS_XG      (WS_WGT + NTOK * 8)        // bf16[16384*512] pair-sorted x (16 MB)
#define WS_WET     (WS_XG + (size_t)NTOK * DIN * 2)  // bf16[8*512*512] (4 MB)

#define GLOAD_LDS16(g, l)                                                     \
  __builtin_amdgcn_global_load_lds(                                           \
      (const __attribute__((address_space(1))) void*)(g),                     \
      (__attribute__((address_space(3))) void*)(l), 16, 0, 0)

// ---------------- histogram tokens by TYPE (independent of routing) --------
__global__ void hist_kernel(const int* __restrict__ atype, int* __restrict__ hist) {
  __shared__ int h[NTYPES];
  int tid = threadIdx.x;
  if (tid < NTYPES) h[tid] = 0;
  __syncthreads();
  int t = blockIdx.x * 256 + tid;
  atomicAdd(&h[atype[t]], 1);
  __syncthreads();
  if (tid < NTYPES && h[tid]) atomicAdd(&hist[tid], h[tid]);
}

// ---- route (top-2 softmax per type) + pair scan + tile map, one block -----
// Tokens of one type all map to one pair, so each type gets a CONTIGUOUS
// subrange inside its pair list: base_type[t] = base_pair[p_t] + within-pair
// offset. Placement then needs only a per-type cursor (no second scan pass).
__global__ void route_scan_kernel(const float* __restrict__ emb,
                                  const float* __restrict__ Wg,
                                  const int* __restrict__ hist,
                                  float* __restrict__ route_w,
                                  int* __restrict__ base_type,
                                  int* __restrict__ cursor,
                                  int* __restrict__ cnt_pair,
                                  int* __restrict__ base_pair,
                                  int* __restrict__ ntile,
                                  int* __restrict__ tmap) {
  __shared__ int s_cnt[NPAIR];
  __shared__ int s_off[NTYPES];
  __shared__ int s_pair[NTYPES];
  int t = threadIdx.x;  // 128 threads = 128 types
  if (t < NPAIR) s_cnt[t] = 0;
  __syncthreads();

  const float* er = emb + (size_t)t * TEBD;
  float lg[NEXP];
#pragma unroll
  for (int e = 0; e < NEXP; ++e) lg[e] = 0.f;
  for (int j = 0; j < TEBD; ++j) {
    float ev = er[j];
#pragma unroll
    for (int e = 0; e < NEXP; ++e) lg[e] += ev * Wg[j * NEXP + e];
  }
  float v0 = -__builtin_inff(), v1 = -__builtin_inff();
  int i0 = 0, i1 = 0;
#pragma unroll
  for (int e = 0; e < NEXP; ++e) {
    float v = lg[e];
    if (v > v0) { v1 = v0; i1 = i0; v0 = v; i0 = e; }
    else if (v > v1) { v1 = v; i1 = e; }
  }
  float d = expf(v1 - v0);
  float inv = 1.f / (1.f + d);
  route_w[t * 2 + 0] = inv;
  route_w[t * 2 + 1] = d * inv;
  int p = i0 * 8 + i1;
  s_pair[t] = p;
  s_off[t] = atomicAdd(&s_cnt[p], hist[t]);  // within-pair offset (any order ok)
  cursor[t] = 0;
  __syncthreads();

  if (t < NPAIR) {
    int b = 0, tb = 0;
    for (int j = 0; j < t; ++j) { b += s_cnt[j]; tb += (s_cnt[j] + 127) >> 7; }
    base_pair[t] = b;
    cnt_pair[t] = s_cnt[t];
    int nt_l = (s_cnt[t] + 127) >> 7;
    for (int i = 0; i < nt_l; ++i) {
      tmap[(tb + i) * 2 + 0] = t;
      tmap[(tb + i) * 2 + 1] = i * 128;
    }
    if (t == NPAIR - 1) ntile[0] = tb + nt_l;
  }
  __syncthreads();
  base_type[t] = base_pair[s_pair[t]] + s_off[t];
}

// ---- fused prep: place+gather+cvt (blocks 0..255) | WeT^T (blocks 256..767)
__global__ void prep_kernel(const float* __restrict__ x,
                            const float* __restrict__ We,
                            const int* __restrict__ atype,
                            const float* __restrict__ route_w,
                            const int* __restrict__ base_type,
                            int* __restrict__ cursor,
                            int* __restrict__ row_map,
                            float* __restrict__ wgt,
                            bf16* __restrict__ xg,
                            bf16* __restrict__ WeT) {
  int bx = blockIdx.x;
  int tid = threadIdx.x;
  if (bx < 256) {
    // ---- place + gather-convert 64 tokens ----
    __shared__ int posS[64];
    int t0 = bx * 64;
    if (tid < 64) {
      int t = t0 + tid;
      int ty = atype[t];
      int pos = base_type[ty] + atomicAdd(&cursor[ty], 1);
      posS[tid] = pos;
      row_map[pos] = t;
      ((float2*)wgt)[pos] = ((const float2*)route_w)[ty];
    }
    __syncthreads();
    int w = tid >> 6, lane = tid & 63;
#pragma unroll
    for (int i = 0; i < 16; ++i) {
      int r = w * 16 + i;
      const float4* p = (const float4*)(x + (size_t)(t0 + r) * DIN + lane * 8);
      float4 a = p[0], b = p[1];
      bf16x8 o;
      o[0] = (bf16)a.x; o[1] = (bf16)a.y; o[2] = (bf16)a.z; o[3] = (bf16)a.w;
      o[4] = (bf16)b.x; o[5] = (bf16)b.y; o[6] = (bf16)b.z; o[7] = (bf16)b.w;
      *(bf16x8*)(xg + (size_t)posS[r] * DIN + lane * 8) = o;
    }
  } else {
    // ---- We[e][k][n] f32 -> WeT[e][n][k] bf16, 64x64 tiles ----
    __shared__ float t[64][65];
    int b2 = bx - 256;        // 512 = 8 experts * 8 * 8 tiles
    int e = b2 >> 6;
    int rem = b2 & 63;
    int kt = (rem >> 3) * 64;
    int nt = (rem & 7) * 64;
    int col = tid & 63;
    int rq = tid >> 6;
#pragma unroll
    for (int r = 0; r < 16; ++r) {
      int row = rq * 16 + r;
      t[row][col] = We[((size_t)e * DIN + kt + row) * DOUT + nt + col];
    }
    __syncthreads();
#pragma unroll
    for (int r = 0; r < 16; ++r) {
      int n = rq * 16 + r;
      WeT[((size_t)e * DOUT + nt + n) * DIN + kt + col] = (bf16)t[col][n];
    }
  }
}

// --------- pair-merged grouped GEMM: one dispatch, both experts ------------
// tile: BM=128 x BN=64, BK=32, 4 waves (2x2 over 128x64), 16x16x32 MFMA.
// Per iter: stage A(8KB, contiguous rows of xg) + B0(4KB) + B1(4KB);
// compute 8 MFMA vs We[e0] and 8 vs We[e1] sharing the A fragments.
// 3-buf LDS (~50 KB -> 3 blocks/CU), counted vmcnt(4) keeps tile t+1 in
// flight. Epilogue: out = w0*tanh(acc0+b0) + w1*tanh(acc1+b1) via fast
// exp2-based tanh (one shared rcp per pair), plain scattered store (each
// token in exactly one pair list -> no memset, no atomics, no RMW).
__global__ __launch_bounds__(256, 3) void moe_gemm_pair_kernel(
    const bf16* __restrict__ xg, const bf16* __restrict__ WeT,
    const float* __restrict__ be, const int* __restrict__ cnt_pair,
    const int* __restrict__ base_pair, const int* __restrict__ ntile,
    const int* __restrict__ tmap, const int* __restrict__ row_map,
    const float* __restrict__ wgt, float* __restrict__ out) {
  int nwork = ntile[0] * 8;
  int f = blockIdx.y * 8 + blockIdx.x;
  if (f >= nwork) return;
  // bijective chunked XCD swizzle over the working range: logical tile L
  // (row-tile-major, 8 col blocks adjacent) -> contiguous chunk per XCD,
  // so same-list A rows and B panels stay L2-local.
  int q = nwork >> 3, r = nwork & 7;
  int xcd = f & 7, idx = f >> 3;
  int L = (xcd < r ? xcd * (q + 1) : r * (q + 1) + (xcd - r) * q) + idx;
  int ti = L >> 3;
  int cx = L & 7;
  int list = tmap[ti * 2 + 0];
  int r0   = tmap[ti * 2 + 1];
  int e0 = list >> 3, e1 = list & 7;
  int nrow = cnt_pair[list] - r0;
  if (nrow > 128) nrow = 128;
  int c0 = cx * 64;
  int arow0 = base_pair[list] + r0;

  __shared__ __align__(16) bf16 As[3][128 * 32];
  __shared__ __align__(16) bf16 B0s[3][64 * 32];
  __shared__ __align__(16) bf16 B1s[3][64 * 32];
  __shared__ int   tokS[128];
  __shared__ float w0S[128], w1S[128];
  __shared__ float be0S[64], be1S[64];

  int tid = threadIdx.x;
  int lane = tid & 63, w = tid >> 6;

  if (tid < 128) {
    int srow = (tid < nrow) ? tid : (nrow - 1);
    int gl = arow0 + srow;
    tokS[tid] = row_map[gl];
    float2 ww = ((const float2*)wgt)[gl];
    w0S[tid] = ww.x;
    w1S[tid] = ww.y;
    if (tid < 64) {
      be0S[tid] = be[e0 * DOUT + c0 + tid];
      be1S[tid] = be[e1 * DOUT + c0 + tid];
    }
  }
  __syncthreads();  // full drain: clean vmcnt slate before pipeline

  // per-lane global sources; chunk swizzle c = cs ^ ((row>>1)&3) keeps the
  // ds_read_b128 side bank-balanced while gload_lds dest stays linear
  const bf16* srcA[2];
#pragma unroll
  for (int j = 0; j < 2; ++j) {
    int slot = w * 128 + j * 64 + lane;
    int row = slot >> 2, cs = slot & 3;
    int c = cs ^ ((row >> 1) & 3);
    int srow = (row < nrow) ? row : (nrow - 1);
    srcA[j] = xg + (size_t)(arow0 + srow) * DIN + c * 8;
  }
  const bf16* srcB0;
  const bf16* srcB1;
  {
    int slot = w * 64 + lane;
    int row = slot >> 2, cs = slot & 3;
    int c = cs ^ ((row >> 1) & 3);
    srcB0 = WeT + ((size_t)e0 * DOUT + c0 + row) * DIN + c * 8;
    srcB1 = WeT + ((size_t)e1 * DOUT + c0 + row) * DIN + c * 8;
  }

  f32x4 acc0[4][2], acc1[4][2];
#pragma unroll
  for (int mi = 0; mi < 4; ++mi)
#pragma unroll
    for (int ni = 0; ni < 2; ++ni) { acc0[mi][ni] = (f32x4)0.f; acc1[mi][ni] = (f32x4)0.f; }

  int wm = (w >> 1) * 64;
  int wn = (w & 1) * 32;
  int r16 = lane & 15, g16 = lane >> 4;

  int offA[4], offB[2];
#pragma unroll
  for (int i = 0; i < 4; ++i) {
    int rA = wm + i * 16 + r16;
    offA[i] = rA * 32 + (g16 ^ ((rA >> 1) & 3)) * 8;
  }
#pragma unroll
  for (int i = 0; i < 2; ++i) {
    int rB = wn + i * 16 + r16;
    offB[i] = rB * 32 + (g16 ^ ((rB >> 1) & 3)) * 8;
  }

  auto stage = [&](int buf) {  // 4 gload_lds per wave, then advance one BK
#pragma unroll
    for (int j = 0; j < 2; ++j) {
      GLOAD_LDS16(srcA[j], &As[buf][(w * 128 + j * 64) * 8]);
      srcA[j] += 32;
    }
    GLOAD_LDS16(srcB0, &B0s[buf][w * 64 * 8]);
    GLOAD_LDS16(srcB1, &B1s[buf][w * 64 * 8]);
    srcB0 += 32;
    srcB1 += 32;
  };

  // prologue: tiles 0 and 1 in flight (8 loads/wave)
  stage(0);
  stage(1);

#pragma unroll
  for (int t = 0; t < 16; ++t) {
    // wait for tile t only: leaves the newer prefetch in flight
    if (t < 15) asm volatile("s_waitcnt vmcnt(4)" ::: "memory");
    else        asm volatile("s_waitcnt vmcnt(0)" ::: "memory");
    __builtin_amdgcn_s_barrier();
    // safe to overwrite buf[(t+2)%3] == buf[(t-1)%3]: all waves passed the
    // barrier, hence finished their iter t-1 ds_reads (MFMA consumed them)
    if (t + 2 < 16) stage((t + 2) % 3);

    int cur = t % 3;
    bf16x8 af[4], b0f[2], b1f[2];
#pragma unroll
    for (int i = 0; i < 4; ++i) af[i] = *(const bf16x8*)&As[cur][offA[i]];
#pragma unroll
    for (int i = 0; i < 2; ++i) b0f[i] = *(const bf16x8*)&B0s[cur][offB[i]];
#pragma unroll
    for (int i = 0; i < 2; ++i) b1f[i] = *(const bf16x8*)&B1s[cur][offB[i]];
    __builtin_amdgcn_s_setprio(1);
#pragma unroll
    for (int mi = 0; mi < 4; ++mi)
#pragma unroll
      for (int ni = 0; ni < 2; ++ni) {
        acc0[mi][ni] = __builtin_amdgcn_mfma_f32_16x16x32_bf16(
            af[mi], b0f[ni], acc0[mi][ni], 0, 0, 0);
        acc1[mi][ni] = __builtin_amdgcn_mfma_f32_16x16x32_bf16(
            af[mi], b1f[ni], acc1[mi][ni], 0, 0, 0);
      }
    __builtin_amdgcn_s_setprio(0);
  }

  // ---- epilogue: out = w0*tanh(acc0+b0) + w1*tanh(acc1+b1), plain store ---
  // fast tanh: tanh(x) = (e^2x - 1)/(e^2x + 1); clamp |x|<=9 (tanh(9)=1-2e-8,
  // exp2 arg <= 26 so no overflow); one v_rcp shared across the pair.
  // |err| ~1e-6 << bf16-quant absmax 9.8e-3. Replaces 2 branchy libm tanhf
  // (~70 VALU instr) with ~15 VALU + 3 trans per element.
#pragma unroll
  for (int mi = 0; mi < 4; ++mi) {
#pragma unroll
    for (int ni = 0; ni < 2; ++ni) {
      f32x4 v0 = acc0[mi][ni];
      f32x4 v1 = acc1[mi][ni];
      int colLocal = wn + ni * 16 + r16;
      float bev0 = be0S[colLocal];
      float bev1 = be1S[colLocal];
#pragma unroll
      for (int r = 0; r < 4; ++r) {
        int lrow = wm + mi * 16 + g16 * 4 + r;
        if (lrow < nrow) {
          float x0 = fminf(9.f, fmaxf(-9.f, v0[r] + bev0)) * 2.885390082f;
          float x1 = fminf(9.f, fmaxf(-9.f, v1[r] + bev1)) * 2.885390082f;
          float e0v, e1v, invd;
          asm("v_exp_f32 %0, %1" : "=v"(e0v) : "v"(x0));  // 2^(2x*log2e)=e^2x
          asm("v_exp_f32 %0, %1" : "=v"(e1v) : "v"(x1));
          float d0 = e0v + 1.f, d1 = e1v + 1.f;
          asm("v_rcp_f32 %0, %1" : "=v"(invd) : "v"(d0 * d1));
          float t0 = (e0v - 1.f) * d1 * invd;
          float t1 = (e1v - 1.f) * d0 * invd;
          out[(size_t)tokS[lrow] * DOUT + c0 + colLocal] =
              t0 * w0S[lrow] + t1 * w1S[lrow];
        }
      }
    }
  }
}

extern "C" void kernel_launch(void* const* d_in, const int* in_sizes, int n_in,
                              void* d_out, int out_size, void* d_ws, size_t ws_size,
                              hipStream_t stream) {
  const float* x    = (const float*)d_in[0];
  const float* emb  = (const float*)d_in[1];
  const int*   aty  = (const int*)d_in[2];
  const float* Wg   = (const float*)d_in[3];
  const float* We   = (const float*)d_in[4];
  const float* be   = (const float*)d_in[5];
  float* out = (float*)d_out;

  char* ws = (char*)d_ws;
  int*   hist      = (int*)(ws + WS_HIST);
  float* route_w   = (float*)(ws + WS_ROUTE_W);
  int*   base_type = (int*)(ws + WS_BASET);
  int*   cursor    = (int*)(ws + WS_CURS);
  int*   cnt_pair  = (int*)(ws + WS_CNTP);
  int*   base_pair = (int*)(ws + WS_BASEP);
  int*   ntile     = (int*)(ws + WS_NTILE);
  int*   tmap      = (int*)(ws + WS_TMAP);
  int*   row_map   = (int*)(ws + WS_RMAP);
  float* wgt       = (float*)(ws + WS_WGT);
  bf16*  xg        = (bf16*)(ws + WS_XG);
  bf16*  WeT       = (bf16*)(ws + WS_WET);

  hipMemsetAsync(hist, 0, NTYPES * sizeof(int), stream);
  hist_kernel<<<NTOK / 256, 256, 0, stream>>>(aty, hist);
  route_scan_kernel<<<1, 128, 0, stream>>>(emb, Wg, hist, route_w, base_type,
                                           cursor, cnt_pair, base_pair, ntile, tmap);
  prep_kernel<<<256 + 512, 256, 0, stream>>>(x, We, aty, route_w, base_type,
                                             cursor, row_map, wgt, xg, WeT);
  // every out element written exactly once -> no memset of out needed
  moe_gemm_pair_kernel<<<dim3(8, MAXTILE), 256, 0, stream>>>(
      xg, WeT, be, cnt_pair, base_pair, ntile, tmap, row_map, wgt, out);
}